// Round 15
// baseline (499.583 us; speedup 1.0000x reference)
//
#include <hip/hip_runtime.h>
#include <math.h>

#define NEXP 32
#define NTOK 256
#define DIMD 768
#define DHID 2048
#define DBOT 256
#define DOUT 768
#define NSLOT 512

// ---------------- gate: logits -> top2 -> normalized weights ----------------
__global__ __launch_bounds__(64) void gate_kernel(
    const float* __restrict__ x, const float* __restrict__ gw,
    int* __restrict__ topk_idx, float* __restrict__ topk_w) {
  const int n = blockIdx.x;
  const int l = threadIdx.x;
  const float* xr = x + n * DIMD;
  float xs[12];
#pragma unroll
  for (int j = 0; j < 12; j++) xs[j] = xr[l + 64 * j];
  float logit[NEXP];
#pragma unroll
  for (int e = 0; e < NEXP; e++) {
    const float* g = gw + e * DIMD;
    float p = 0.f;
#pragma unroll
    for (int j = 0; j < 12; j++) p = fmaf(xs[j], g[l + 64 * j], p);
#pragma unroll
    for (int m = 1; m < 64; m <<= 1) p += __shfl_xor(p, m);
    logit[e] = p;
  }
  int i0 = 0; float m0 = logit[0];
#pragma unroll
  for (int e = 1; e < NEXP; e++) { if (logit[e] > m0) { m0 = logit[e]; i0 = e; } }
  int i1 = -1; float m1 = -3.4e38f;
#pragma unroll
  for (int e = 0; e < NEXP; e++) { if (e != i0 && logit[e] > m1) { m1 = logit[e]; i1 = e; } }
  const float e1 = expf(m1 - m0);
  const float w0 = 1.f / (1.f + e1);
  const float w1 = e1 * w0;
  if (l == 0) {
    topk_idx[2 * n] = i0; topk_idx[2 * n + 1] = i1;
    topk_w[2 * n] = w0;  topk_w[2 * n + 1] = w1;
  }
}

// ---------------- build per-expert token lists + maps ----------------
__global__ __launch_bounds__(256) void build_lists(
    const int* __restrict__ topk_idx,
    int* __restrict__ counts, int* __restrict__ offsets,
    int* __restrict__ tok_list, int* __restrict__ tok2slot) {
  __shared__ int cnt[NEXP], base[NEXP], fill[NEXP];
  const int t = threadIdx.x;
  if (t < NEXP) { cnt[t] = 0; fill[t] = 0; }
  __syncthreads();
  const int e0 = topk_idx[2 * t], e1 = topk_idx[2 * t + 1];
  atomicAdd(&cnt[e0], 1);
  atomicAdd(&cnt[e1], 1);
  __syncthreads();
  if (t == 0) { int s = 0; for (int i = 0; i < NEXP; i++) { base[i] = s; s += cnt[i]; } }
  __syncthreads();
  const int p0 = atomicAdd(&fill[e0], 1);
  tok_list[base[e0] + p0] = t; tok2slot[2 * t] = base[e0] + p0;
  const int p1 = atomicAdd(&fill[e1], 1);
  tok_list[base[e1] + p1] = t; tok2slot[2 * t + 1] = base[e1] + p1;
  if (t < NEXP) { counts[t] = cnt[t]; offsets[t] = base[t]; }
}

__device__ __forceinline__ float gelu_f(float v) {
  return 0.5f * v * (1.f + erff(v * 0.70710678118654752f));
}

__device__ __forceinline__ float lane_bc(float v, int r) {  // broadcast lane r (literal)
  return __int_as_float(__builtin_amdgcn_readlane(__float_as_int(v), r));
}

#define FMA4(A, XS, WV) \
  A.x = fmaf(XS, WV.x, A.x); A.y = fmaf(XS, WV.y, A.y); \
  A.z = fmaf(XS, WV.z, A.z); A.w = fmaf(XS, WV.w, A.w)

// ---------------- expert FF layer: W via global_load_lds; ACT in registers ----------------
// Block 512 thr = 8 waves; wave owns 4 tokens; lane owns 4 cols of a 256-col tile.
// Act for a 64-row section: lane r holds float4 (act[tok0..3][row r]) — NO act LDS.
// Per row per wave: 1 ds_read_b128 (W, conflict-free) + 4 v_readlane (VALU->SGPR)
// + 16 v_fma with SGPR act operand. LDS pipe/row/CU: 8x12=96 cy (R13 was 192 ->
// LDS-bound ~2.1 TB/s). Now HBM fair-share (2.6us/64KB section) is the binding pipe.
// W double-buffered 2x64KB; act loads issued early (T14). Direct stores, no atomics.
// MODE 0: B1 = gelu(x(gather) @ W1 + b1)     grid (8,32)  K=768
// MODE 1: B2 = gelu(B1 @ W2 + b2)            grid (8,32)  K=2048
// MODE 2: zpart[kb] = B2 @ W3 K-slice        grid (8,32)  K=256/block
// MODE 3: OutS = (sum_k zpart[k] + b3) @ Wl  grid (3,32)  K=256 (zsum folded)
template <int MODE>
__global__ __launch_bounds__(512, 2) void ff_kernel(
    const float* __restrict__ Ain, const float* __restrict__ W,
    const float* __restrict__ Bias, float* __restrict__ Out,
    const float* __restrict__ zpart,
    const int* __restrict__ offsets, const int* __restrict__ counts,
    const int* __restrict__ tok_list) {
  constexpr int NCT   = (MODE <= 1) ? 2048 : (MODE == 2) ? 256 : 768;
  constexpr int KFULL = (MODE == 0) ? 768 : (MODE == 3) ? 256 : 2048;
  constexpr int INS   = (MODE == 0) ? DIMD : DHID;
  constexpr int NSEC  = (MODE == 0) ? 12 : (MODE == 1) ? 32 : 4;   // all even
  __shared__ float Wlds[2 * 64 * 256];   // 128 KB dbuf weight tile
  const int tid  = threadIdx.x;
  const int lane = tid & 63;
  const int wave = tid >> 6;
  const int e    = blockIdx.y;
  const int kb   = (MODE == 2) ? blockIdx.x : 0;
  const int ct   = (MODE == 2) ? 0 : blockIdx.x;
  const int kbase = kb * 256;
  const int cnt = counts[e];
  const int off = offsets[e];
  const int col = ct * 256 + lane * 4;
  const float* Wsrc = W + (size_t)e * KFULL * NCT + (size_t)ct * 256;

  for (int tc0 = 0; tc0 < cnt; tc0 += 32) {
    const int tcn = min(32, cnt - tc0);
    // this wave's 4 token rows (act sources)
    const float* Arow[4];
    int slots[4];
#pragma unroll
    for (int t = 0; t < 4; t++) {
      const int tt = wave * 4 + t;
      slots[t] = off + tc0 + tt;
      if (tt < tcn && MODE != 3) {
        const int row = (MODE == 0) ? tok_list[slots[t]] : slots[t];
        Arow[t] = Ain + (size_t)row * INS + kbase;
      } else {
        Arow[t] = nullptr;
      }
    }

    float4 acc[4];
#pragma unroll
    for (int t = 0; t < 4; t++) acc[t] = {0.f, 0.f, 0.f, 0.f};

    // ---- act load: lane holds act[tok0..3][row lane] of section s ----
    auto a_load = [&](int s, float4& dst) {
      const int c = s * 64 + lane;
      float q[4];
      if (MODE == 3) {
#pragma unroll
        for (int t = 0; t < 4; t++) {
          if (wave * 4 + t < tcn) {
            float v = Bias[(size_t)e * DBOT + c];
#pragma unroll
            for (int k = 0; k < 8; k++)
              v += zpart[((size_t)k * NSLOT + slots[t]) * DBOT + c];
            q[t] = v;
          } else q[t] = 0.f;
        }
      } else {
#pragma unroll
        for (int t = 0; t < 4; t++) q[t] = Arow[t] ? Arow[t][c] : 0.f;
      }
      dst = {q[0], q[1], q[2], q[3]};
    };
    // ---- W stage: 64 rows x 1 KB via 8 gload_lds per wave ----
    auto w_issue = [&](int b, int s) {
      float* wl = Wlds + b * 16384;
      const float* src = Wsrc + (size_t)(kbase + s * 64) * NCT;
#pragma unroll
      for (int c = 0; c < 8; c++) {
        const int r = c * 8 + wave;
        __builtin_amdgcn_global_load_lds(
            (const __attribute__((address_space(1))) void*)(src + (size_t)r * NCT + lane * 4),
            (__attribute__((address_space(3))) void*)(wl + r * 256),
            16, 0, 0);
      }
    };

    // ---- prologue ----
    float4 av, av_next;
    a_load(0, av);
    w_issue(0, 0);
    __syncthreads();

    // ---- section loop ----
    for (int s = 0; s < NSEC; s++) {
      const int b = s & 1;
      if (s + 1 < NSEC) {
        a_load(s + 1, av_next);    // global loads fly under compute
        w_issue(b ^ 1, s + 1);     // deep fire-and-forget queue
      }
      {  // ---- compute 64 rows: act via readlane (scalar operand), W via LDS ----
        const float* wl = Wlds + b * 16384 + lane * 4;
#pragma unroll
        for (int r = 0; r < 64; r++) {
          const float4 wv = *(const float4*)(wl + r * 256);
          const float a0 = lane_bc(av.x, r);
          const float a1 = lane_bc(av.y, r);
          const float a2 = lane_bc(av.z, r);
          const float a3 = lane_bc(av.w, r);
          FMA4(acc[0], a0, wv);
          FMA4(acc[1], a1, wv);
          FMA4(acc[2], a2, wv);
          FMA4(acc[3], a3, wv);
        }
      }
      av = av_next;
      __syncthreads();   // drains next section's stages; Wlds[b] free for reuse
    }

    // ---- epilogue: direct stores, static indexing ----
    float4 bv = {0.f, 0.f, 0.f, 0.f};
    if (MODE <= 1) bv = *(const float4*)(Bias + (size_t)e * NCT + col);
#pragma unroll
    for (int tt = 0; tt < 4; tt++) {
      if (wave * 4 + tt < tcn) {
        const int os = slots[tt];
        float4 o = acc[tt];
        if (MODE <= 1) {
          o.x = gelu_f(o.x + bv.x); o.y = gelu_f(o.y + bv.y);
          o.z = gelu_f(o.z + bv.z); o.w = gelu_f(o.w + bv.w);
          *(float4*)(Out + (size_t)os * NCT + col) = o;
        } else if (MODE == 2) {
          *(float4*)(Out + ((size_t)kb * NSLOT + os) * DBOT + lane * 4) = o;
        } else {
          *(float4*)(Out + (size_t)os * DOUT + col) = o;
        }
      }
    }
  }
}

// ---------------- combine: y[n] = sum_k w_k * (OutS[slot_k] + bl[e_k]) ----------------
__global__ __launch_bounds__(192) void combine_kernel(
    const float* __restrict__ OutS, const float* __restrict__ bl,
    const int* __restrict__ topk_idx, const float* __restrict__ topk_w,
    const int* __restrict__ tok2slot, float* __restrict__ y) {
  const int n = blockIdx.x;
  const int c = threadIdx.x * 4;
  const int s0 = tok2slot[2 * n], s1 = tok2slot[2 * n + 1];
  const int e0 = topk_idx[2 * n], e1 = topk_idx[2 * n + 1];
  const float w0 = topk_w[2 * n], w1 = topk_w[2 * n + 1];
  const float4 a  = *(const float4*)(OutS + (size_t)s0 * DOUT + c);
  const float4 b  = *(const float4*)(OutS + (size_t)s1 * DOUT + c);
  const float4 ba = *(const float4*)(bl + (size_t)e0 * DOUT + c);
  const float4 bb = *(const float4*)(bl + (size_t)e1 * DOUT + c);
  float4 o;
  o.x = w0 * (a.x + ba.x) + w1 * (b.x + bb.x);
  o.y = w0 * (a.y + ba.y) + w1 * (b.y + bb.y);
  o.z = w0 * (a.z + ba.z) + w1 * (b.z + bb.z);
  o.w = w0 * (a.w + ba.w) + w1 * (b.w + bb.w);
  *(float4*)(y + (size_t)n * DOUT + c) = o;
}

extern "C" void kernel_launch(void* const* d_in, const int* in_sizes, int n_in,
                              void* d_out, int out_size, void* d_ws, size_t ws_size,
                              hipStream_t stream) {
  const float* x  = (const float*)d_in[0];
  const float* gw = (const float*)d_in[1];
  const float* W1 = (const float*)d_in[2];
  const float* b1 = (const float*)d_in[3];
  const float* W2 = (const float*)d_in[4];
  const float* b2 = (const float*)d_in[5];
  const float* W3 = (const float*)d_in[6];
  const float* b3 = (const float*)d_in[7];
  const float* Wl = (const float*)d_in[8];
  const float* bl = (const float*)d_in[9];
  float* y  = (float*)d_out;
  float* ws = (float*)d_ws;

  float* topk_w   = ws;                    // 512 f
  int*   topk_idx = (int*)(ws + 512);      // 512 i
  int*   counts   = (int*)(ws + 1024);     // 32 i
  int*   offsets  = (int*)(ws + 1056);     // 32 i
  int*   tok_list = (int*)(ws + 1088);     // 512 i
  int*   tok2slot = (int*)(ws + 1600);     // 512 i
  float* B1    = ws + 4096;                        // 512*2048
  float* B2    = B1 + (size_t)NSLOT * DHID;        // 512*2048
  float* zpart = B2 + (size_t)NSLOT * DHID;        // 8*512*256
  float* OutS  = zpart + (size_t)8 * NSLOT * DBOT; // 512*768

  gate_kernel<<<NTOK, 64, 0, stream>>>(x, gw, topk_idx, topk_w);
  build_lists<<<1, 256, 0, stream>>>(topk_idx, counts, offsets, tok_list, tok2slot);
  // L1: B1 = gelu(x @ W1 + b1)        (8 coltiles x 32 experts, K=768)
  ff_kernel<0><<<dim3(8, 32), 512, 0, stream>>>(x,  W1, b1, B1, nullptr,
                                                offsets, counts, tok_list);
  // L2: B2 = gelu(B1 @ W2 + b2)       (8 coltiles x 32 experts, K=2048)
  ff_kernel<1><<<dim3(8, 32), 512, 0, stream>>>(B1, W2, b2, B2, nullptr,
                                                offsets, counts, tok_list);
  // L3: zpart[kb] = B2 @ W3 slice     (8 K-slices x 32 experts)
  ff_kernel<2><<<dim3(8, 32), 512, 0, stream>>>(B2, W3, nullptr, zpart, nullptr,
                                                offsets, counts, tok_list);
  // L4: OutS = (sum zpart + b3) @ Wl  (3 coltiles x 32 experts, K=256; zsum folded)
  ff_kernel<3><<<dim3(3, 32), 512, 0, stream>>>(nullptr, Wl, b3, OutS, zpart,
                                                offsets, counts, tok_list);
  // combine: y = sum_k w_k (OutS + bl)
  combine_kernel<<<NTOK, 192, 0, stream>>>(OutS, bl, topk_idx, topk_w, tok2slot, y);
}

// Round 16
// 424.500 us; speedup vs baseline: 1.1769x; 1.1769x over previous
//
#include <hip/hip_runtime.h>
#include <math.h>

#define NEXP 32
#define NTOK 256
#define DIMD 768
#define DHID 2048
#define DBOT 256
#define DOUT 768
#define NSLOT 512

// ---------------- gate: logits -> top2 -> normalized weights ----------------
__global__ __launch_bounds__(64) void gate_kernel(
    const float* __restrict__ x, const float* __restrict__ gw,
    int* __restrict__ topk_idx, float* __restrict__ topk_w) {
  const int n = blockIdx.x;
  const int l = threadIdx.x;
  const float* xr = x + n * DIMD;
  float xs[12];
#pragma unroll
  for (int j = 0; j < 12; j++) xs[j] = xr[l + 64 * j];
  float logit[NEXP];
#pragma unroll
  for (int e = 0; e < NEXP; e++) {
    const float* g = gw + e * DIMD;
    float p = 0.f;
#pragma unroll
    for (int j = 0; j < 12; j++) p = fmaf(xs[j], g[l + 64 * j], p);
#pragma unroll
    for (int m = 1; m < 64; m <<= 1) p += __shfl_xor(p, m);
    logit[e] = p;
  }
  int i0 = 0; float m0 = logit[0];
#pragma unroll
  for (int e = 1; e < NEXP; e++) { if (logit[e] > m0) { m0 = logit[e]; i0 = e; } }
  int i1 = -1; float m1 = -3.4e38f;
#pragma unroll
  for (int e = 0; e < NEXP; e++) { if (e != i0 && logit[e] > m1) { m1 = logit[e]; i1 = e; } }
  const float e1 = expf(m1 - m0);
  const float w0 = 1.f / (1.f + e1);
  const float w1 = e1 * w0;
  if (l == 0) {
    topk_idx[2 * n] = i0; topk_idx[2 * n + 1] = i1;
    topk_w[2 * n] = w0;  topk_w[2 * n + 1] = w1;
  }
}

// ---------------- build per-expert token lists + maps ----------------
__global__ __launch_bounds__(256) void build_lists(
    const int* __restrict__ topk_idx,
    int* __restrict__ counts, int* __restrict__ offsets,
    int* __restrict__ tok_list, int* __restrict__ tok2slot,
    int* __restrict__ slot_expert) {
  __shared__ int cnt[NEXP], base[NEXP], fill[NEXP];
  const int t = threadIdx.x;
  if (t < NEXP) { cnt[t] = 0; fill[t] = 0; }
  __syncthreads();
  const int e0 = topk_idx[2 * t], e1 = topk_idx[2 * t + 1];
  atomicAdd(&cnt[e0], 1);
  atomicAdd(&cnt[e1], 1);
  __syncthreads();
  if (t == 0) { int s = 0; for (int i = 0; i < NEXP; i++) { base[i] = s; s += cnt[i]; } }
  __syncthreads();
  const int p0 = atomicAdd(&fill[e0], 1);
  tok_list[base[e0] + p0] = t; tok2slot[2 * t] = base[e0] + p0;
  slot_expert[base[e0] + p0] = e0;
  const int p1 = atomicAdd(&fill[e1], 1);
  tok_list[base[e1] + p1] = t; tok2slot[2 * t + 1] = base[e1] + p1;
  slot_expert[base[e1] + p1] = e1;
  if (t < NEXP) { counts[t] = cnt[t]; offsets[t] = base[t]; }
}

__device__ __forceinline__ float gelu_f(float v) {
  return 0.5f * v * (1.f + erff(v * 0.70710678118654752f));
}

#define FMA4(A, XS, WV) \
  A.x = fmaf(XS, WV.x, A.x); A.y = fmaf(XS, WV.y, A.y); \
  A.z = fmaf(XS, WV.z, A.z); A.w = fmaf(XS, WV.w, A.w)
#define ADD4(Q, P) Q.x += P.x; Q.y += P.y; Q.z += P.z; Q.w += P.w

// ---------------- expert FF K-slice: W via global_load_lds, 72 KB LDS ----------------
// KEY CHANGE vs R13: 32-row sections -> 72 KB LDS -> TWO blocks/CU. At 1 block/CU the
// __syncthreads vmcnt(0) drain idled the whole CU for each section's un-overlapped load
// remainder (m97/m114: implicit overlap needs multi-block occupancy). Every layer is
// K-split across the grid into PART buffers (no atomics, R11 lesson); parts are summed
// in cheap combine passes. Per row per wave: 1 distinct W ds_read_b128 + 1 uniform act
// b128 + 16 FMA (the per-wave instruction minimum). 512 thr = 8 waves x 4 tokens.
// MODE 0: B1part[kb] = x(gather) @ W1[kslice]    grid (16,32): 8ct x 2kb, KBLK=384
// MODE 1: B2part[kb] = B1 @ W2[kslice]           grid (16,32): 8ct x 2kb, KBLK=1024
// MODE 2: zpart[kb]  = B2 @ W3[kslice]           grid (16,32): 1ct x 16kb, KBLK=128
// MODE 3: OutSp[kb]  = zsum @ Wl[kslice]         grid (6,32):  3ct x 2kb, KBLK=128
template <int MODE>
__global__ __launch_bounds__(512, 2) void ff_kernel(
    const float* __restrict__ Ain, const float* __restrict__ W,
    float* __restrict__ Out,
    const int* __restrict__ offsets, const int* __restrict__ counts,
    const int* __restrict__ tok_list) {
  constexpr int NCT   = (MODE <= 1) ? 2048 : (MODE == 2) ? 256 : 768;
  constexpr int KBLK  = (MODE == 0) ? 384 : (MODE == 1) ? 1024 : 128;
  constexpr int NSEC  = KBLK / 32;
  constexpr int KFULL = (MODE == 0) ? 768 : (MODE == 3) ? 256 : 2048;
  constexpr int INS   = (MODE == 0) ? DIMD : (MODE == 3) ? DBOT : DHID;
  constexpr int CT    = (MODE <= 1) ? 8 : (MODE == 2) ? 1 : 3;
  __shared__ float Wlds[2 * 32 * 256];   // 64 KB dbuf weight tile (32 rows x 256 cols)
  __shared__ float act_t[2 * 32 * 32];   // 8 KB dbuf act (transposed [row][tok])
  const int tid  = threadIdx.x;
  const int lane = tid & 63;
  const int wave = tid >> 6;           // 8 waves x 4 tokens
  const int e    = blockIdx.y;
  const int ct   = blockIdx.x % CT;
  const int kb   = blockIdx.x / CT;
  const int kbase = kb * KBLK;
  const int cnt = counts[e];
  const int off = offsets[e];
  const int col = ct * 256 + lane * 4;
  const float* Wsrc = W + (size_t)e * KFULL * NCT + (size_t)ct * 256;
  float* Outp = Out + (size_t)kb * NSLOT * NCT;
  const int tok  = tid & 31;
  const int kseg = tid >> 5;           // 0..15: stages act rows kseg*2, kseg*2+1

  for (int tc0 = 0; tc0 < cnt; tc0 += 32) {
    const int tcn = min(32, cnt - tc0);
    const int slot = off + tc0 + tok;
    const float* Arow = nullptr;
    if (tok < tcn) {
      const int row = (MODE == 0) ? tok_list[slot] : slot;
      Arow = Ain + (size_t)row * INS + kbase;
    }

    float4 acc[4];
#pragma unroll
    for (int t = 0; t < 4; t++) acc[t] = {0.f, 0.f, 0.f, 0.f};

    auto a_load = [&](int s) -> float2 {
      if (Arow) return *(const float2*)(Arow + s * 32 + kseg * 2);
      return {0.f, 0.f};
    };
    auto w_issue = [&](int b, int s) {   // 32 rows x 1 KB: 4 gload_lds per wave
      float* wl = Wlds + b * 8192;
      const float* src = Wsrc + (size_t)(kbase + s * 32) * NCT;
#pragma unroll
      for (int c = 0; c < 4; c++) {
        const int r = c * 8 + wave;
        __builtin_amdgcn_global_load_lds(
            (const __attribute__((address_space(1))) void*)(src + (size_t)r * NCT + lane * 4),
            (__attribute__((address_space(3))) void*)(wl + r * 256),
            16, 0, 0);
      }
    };
    auto a_write = [&](int b, float2 v) {
      float* at = act_t + b * 1024;
      at[(kseg * 2 + 0) * 32 + tok] = v.x;
      at[(kseg * 2 + 1) * 32 + tok] = v.y;
    };

    // ---- prologue: stage section 0 ----
    {
      float2 v0 = a_load(0);
      w_issue(0, 0);
      a_write(0, v0);
    }
    __syncthreads();

    // ---- section loop ----
    for (int s = 0; s < NSEC; s++) {
      const int b = s & 1;
      float2 vn;
      if (s + 1 < NSEC) {
        vn = a_load(s + 1);        // global loads fly under compute
        w_issue(b ^ 1, s + 1);     // deep fire-and-forget queue
      }
      {  // ---- compute 32 rows ----
        const float* wl = Wlds + b * 8192 + lane * 4;
        const float* at = act_t + b * 1024 + wave * 4;
#pragma unroll 8
        for (int r = 0; r < 32; r++) {
          const float4 wv = *(const float4*)(wl + r * 256);   // distinct 1 KB/wave
          const float4 xv = *(const float4*)(at + r * 32);    // uniform broadcast
          FMA4(acc[0], xv.x, wv);
          FMA4(acc[1], xv.y, wv);
          FMA4(acc[2], xv.z, wv);
          FMA4(acc[3], xv.w, wv);
        }
      }
      if (s + 1 < NSEC) a_write(b ^ 1, vn);
      __syncthreads();   // the other resident block computes during this drain
    }

    // ---- epilogue: raw partial-sum stores (bias/gelu in combine passes) ----
#pragma unroll
    for (int tt = 0; tt < 4; tt++) {
      if (wave * 4 + tt < tcn) {
        const int os = off + tc0 + wave * 4 + tt;
        *(float4*)(Outp + (size_t)os * NCT + col) = acc[tt];
      }
    }
    __syncthreads();   // buffers free before next chunk
  }
}

// ---------------- h_combine: B = gelu(P0 + P1 + bias[e]) ----------------
__global__ __launch_bounds__(256) void h_combine(
    const float* __restrict__ P0, const float* __restrict__ P1,
    const float* __restrict__ bias, const int* __restrict__ slot_expert,
    float* __restrict__ Bout) {
  const int slot = blockIdx.x;
  const int e = slot_expert[slot];
  const int c0 = threadIdx.x * 8;
#pragma unroll
  for (int j = 0; j < 8; j += 4) {
    float4 a = *(const float4*)(P0 + (size_t)slot * DHID + c0 + j);
    const float4 b = *(const float4*)(P1 + (size_t)slot * DHID + c0 + j);
    const float4 bb = *(const float4*)(bias + (size_t)e * DHID + c0 + j);
    float4 o;
    o.x = gelu_f(a.x + b.x + bb.x); o.y = gelu_f(a.y + b.y + bb.y);
    o.z = gelu_f(a.z + b.z + bb.z); o.w = gelu_f(a.w + b.w + bb.w);
    *(float4*)(Bout + (size_t)slot * DHID + c0 + j) = o;
  }
}

// ---------------- zsum: zsum[slot] = sum_16 zpart + b3[e] ----------------
__global__ __launch_bounds__(64) void zsum_kernel(
    const float* __restrict__ zpart, const float* __restrict__ b3,
    const int* __restrict__ slot_expert, float* __restrict__ zsum) {
  const int slot = blockIdx.x;
  const int c = threadIdx.x * 4;
  const int e = slot_expert[slot];
  float4 q = *(const float4*)(b3 + (size_t)e * DBOT + c);
#pragma unroll
  for (int k = 0; k < 16; k++) {
    const float4 p = *(const float4*)(zpart + ((size_t)k * NSLOT + slot) * DBOT + c);
    ADD4(q, p);
  }
  *(float4*)(zsum + (size_t)slot * DBOT + c) = q;
}

// ------- combine: y[n] = sum_k w_k * (OutSp0[slot_k] + OutSp1[slot_k] + bl[e_k]) -------
__global__ __launch_bounds__(192) void combine_kernel(
    const float* __restrict__ OP0, const float* __restrict__ OP1,
    const float* __restrict__ bl,
    const int* __restrict__ topk_idx, const float* __restrict__ topk_w,
    const int* __restrict__ tok2slot, float* __restrict__ y) {
  const int n = blockIdx.x;
  const int c = threadIdx.x * 4;
  const int s0 = tok2slot[2 * n], s1 = tok2slot[2 * n + 1];
  const int e0 = topk_idx[2 * n], e1 = topk_idx[2 * n + 1];
  const float w0 = topk_w[2 * n], w1 = topk_w[2 * n + 1];
  float4 a = *(const float4*)(OP0 + (size_t)s0 * DOUT + c);
  const float4 a1 = *(const float4*)(OP1 + (size_t)s0 * DOUT + c);
  const float4 ba = *(const float4*)(bl + (size_t)e0 * DOUT + c);
  float4 b = *(const float4*)(OP0 + (size_t)s1 * DOUT + c);
  const float4 b1 = *(const float4*)(OP1 + (size_t)s1 * DOUT + c);
  const float4 bb = *(const float4*)(bl + (size_t)e1 * DOUT + c);
  float4 o;
  o.x = w0 * (a.x + a1.x + ba.x) + w1 * (b.x + b1.x + bb.x);
  o.y = w0 * (a.y + a1.y + ba.y) + w1 * (b.y + b1.y + bb.y);
  o.z = w0 * (a.z + a1.z + ba.z) + w1 * (b.z + b1.z + bb.z);
  o.w = w0 * (a.w + a1.w + ba.w) + w1 * (b.w + b1.w + bb.w);
  *(float4*)(y + (size_t)n * DOUT + c) = o;
}

extern "C" void kernel_launch(void* const* d_in, const int* in_sizes, int n_in,
                              void* d_out, int out_size, void* d_ws, size_t ws_size,
                              hipStream_t stream) {
  const float* x  = (const float*)d_in[0];
  const float* gw = (const float*)d_in[1];
  const float* W1 = (const float*)d_in[2];
  const float* b1 = (const float*)d_in[3];
  const float* W2 = (const float*)d_in[4];
  const float* b2 = (const float*)d_in[5];
  const float* W3 = (const float*)d_in[6];
  const float* b3 = (const float*)d_in[7];
  const float* Wl = (const float*)d_in[8];
  const float* bl = (const float*)d_in[9];
  float* y  = (float*)d_out;
  float* ws = (float*)d_ws;

  float* topk_w   = ws;                    // 512 f
  int*   topk_idx = (int*)(ws + 512);      // 512 i
  int*   counts   = (int*)(ws + 1024);     // 32 i
  int*   offsets  = (int*)(ws + 1056);     // 32 i
  int*   tok_list = (int*)(ws + 1088);     // 512 i
  int*   tok2slot = (int*)(ws + 1600);     // 512 i
  int*   slot_exp = (int*)(ws + 2112);     // 512 i
  const size_t M = (size_t)NSLOT * DHID;   // 1048576
  float* B1p   = ws + 4096;                // 2 parts
  float* B1    = B1p + 2 * M;
  float* B2p   = B1 + M;                   // 2 parts
  float* B2    = B2p + 2 * M;
  float* zpart = B2 + M;                   // 16*512*256
  float* zsum  = zpart + (size_t)16 * NSLOT * DBOT;
  float* OutSp = zsum + (size_t)NSLOT * DBOT;   // 2 parts of 512*768

  gate_kernel<<<NTOK, 64, 0, stream>>>(x, gw, topk_idx, topk_w);
  build_lists<<<1, 256, 0, stream>>>(topk_idx, counts, offsets, tok_list, tok2slot, slot_exp);
  // L1: B1part = x @ W1 kslices       (8ct x 2kb x 32e = 512 blocks, 2/CU)
  ff_kernel<0><<<dim3(16, 32), 512, 0, stream>>>(x, W1, B1p, offsets, counts, tok_list);
  h_combine<<<NSLOT, 256, 0, stream>>>(B1p, B1p + M, b1, slot_exp, B1);
  // L2: B2part = B1 @ W2 kslices      (8ct x 2kb x 32e = 512 blocks, 2/CU)
  ff_kernel<1><<<dim3(16, 32), 512, 0, stream>>>(B1, W2, B2p, offsets, counts, tok_list);
  h_combine<<<NSLOT, 256, 0, stream>>>(B2p, B2p + M, b2, slot_exp, B2);
  // L3: zpart = B2 @ W3 kslices       (16kb x 32e = 512 blocks)
  ff_kernel<2><<<dim3(16, 32), 512, 0, stream>>>(B2, W3, zpart, offsets, counts, tok_list);
  zsum_kernel<<<NSLOT, 64, 0, stream>>>(zpart, b3, slot_exp, zsum);
  // L4: OutSp = zsum @ Wl kslices     (3ct x 2kb x 32e = 192 blocks)
  ff_kernel<3><<<dim3(6, 32), 512, 0, stream>>>(zsum, Wl, OutSp, offsets, counts, tok_list);
  // combine: y = sum_k w_k (OutSp0 + OutSp1 + bl)
  combine_kernel<<<NTOK, 192, 0, stream>>>(OutSp, OutSp + (size_t)NSLOT * DOUT, bl,
                                           topk_idx, topk_w, tok2slot, y);
}